// Round 1
// baseline (1707.880 us; speedup 1.0000x reference)
//
#include <hip/hip_runtime.h>

#define NN 100000
#define NE 3200000
#define NG 2048
#define FIN 4
#define HD 64

// ---------------- kernels ----------------

__global__ void deg_count_k(const int* __restrict__ dst, int* __restrict__ cnt, int e) {
    int t = blockIdx.x * blockDim.x + threadIdx.x;
    if (t < e) atomicAdd(&cnt[dst[t]], 1);
}

__global__ void dinv_k(const int* __restrict__ cnt, float* __restrict__ dinv, int n) {
    int t = blockIdx.x * blockDim.x + threadIdx.x;
    if (t < n) dinv[t] = rsqrtf((float)cnt[t] + 1.0f);
}

// xw = x @ W1, x is [n, FIN], W1 is [FIN, HD]
__global__ void xw1_k(const float* __restrict__ x, const float* __restrict__ W,
                      float* __restrict__ out, int n) {
    int t = blockIdx.x * blockDim.x + threadIdx.x;
    if (t >= n * HD) return;
    int node = t >> 6, h = t & 63;
    const float* xp = x + node * FIN;
    float s = 0.f;
#pragma unroll
    for (int k = 0; k < FIN; ++k) s = fmaf(xp[k], W[k * HD + h], s);
    out[t] = s;
}

// xw = hin @ W2, hin is [n, HD], W2 is [HD, HD] (staged in LDS)
__global__ void xw2_k(const float* __restrict__ hin, const float* __restrict__ W,
                      float* __restrict__ out, int n) {
    __shared__ float w[HD * HD];
    for (int i = threadIdx.x; i < HD * HD; i += blockDim.x) w[i] = W[i];
    __syncthreads();
    int t = blockIdx.x * blockDim.x + threadIdx.x;
    if (t >= n * HD) return;
    int node = t >> 6, h = t & 63;
    const float* hp = hin + node * HD;
    float s = 0.f;
#pragma unroll
    for (int k = 0; k < HD; ++k) s = fmaf(hp[k], w[k * HD + h], s);
    out[t] = s;
}

// per-(edge, feature): agg[dst,h] += dinv[src]*dinv[dst] * xw[src,h]
__global__ void scatter_k(const float* __restrict__ xw, const int* __restrict__ src,
                          const int* __restrict__ dst, const float* __restrict__ dinv,
                          float* __restrict__ agg) {
    long long t = (long long)blockIdx.x * blockDim.x + threadIdx.x;
    if (t >= (long long)NE * HD) return;
    int e = (int)(t >> 6), h = (int)(t & 63);
    int s = src[e], d = dst[e];
    float coef = dinv[s] * dinv[d];
    atomicAdd(&agg[(long long)d * HD + h], coef * xw[(long long)s * HD + h]);
}

// out = relu(agg + xw*dinv^2 + bias)
__global__ void combine_k(const float* __restrict__ agg, const float* __restrict__ xw,
                          const float* __restrict__ dinv, const float* __restrict__ bias,
                          float* __restrict__ out, int n) {
    int t = blockIdx.x * blockDim.x + threadIdx.x;
    if (t >= n * HD) return;
    int node = t >> 6, h = t & 63;
    float di = dinv[node];
    float v = agg[t] + xw[t] * di * di + bias[h];
    out[t] = fmaxf(v, 0.f);
}

__global__ void pool_k(const float* __restrict__ h2, const int* __restrict__ batch,
                       float* __restrict__ pool, int n) {
    int t = blockIdx.x * blockDim.x + threadIdx.x;
    if (t >= n * HD) return;
    int node = t >> 6, h = t & 63;
    atomicAdd(&pool[(long long)batch[node] * HD + h], h2[t]);
}

__global__ void cnt_k(const int* __restrict__ batch, float* __restrict__ pcnt, int n) {
    int t = blockIdx.x * blockDim.x + threadIdx.x;
    if (t < n) atomicAdd(&pcnt[batch[t]], 1.0f);
}

// one wave (64 threads) per graph: out[g] = dot(pool[g]/cnt[g], Wlin) + blin
__global__ void final_k(const float* __restrict__ pool, const float* __restrict__ pcnt,
                        const float* __restrict__ Wlin, const float* __restrict__ blin,
                        float* __restrict__ out) {
    int g = blockIdx.x;
    int lane = threadIdx.x;
    float v = pool[g * HD + lane] * Wlin[lane];
#pragma unroll
    for (int off = 32; off > 0; off >>= 1) v += __shfl_down(v, off);
    if (lane == 0) out[g] = v / fmaxf(pcnt[g], 1.0f) + blin[0];
}

// ---------------- launch ----------------

extern "C" void kernel_launch(void* const* d_in, const int* in_sizes, int n_in,
                              void* d_out, int out_size, void* d_ws, size_t ws_size,
                              hipStream_t stream) {
    const float* x    = (const float*)d_in[0];
    const int*   ei   = (const int*)d_in[1];   // [2, E] flat: src = ei[0..E), dst = ei[E..2E)
    const int*   bat  = (const int*)d_in[2];
    const float* W1   = (const float*)d_in[3];
    const float* b1   = (const float*)d_in[4];
    const float* W2   = (const float*)d_in[5];
    const float* b2   = (const float*)d_in[6];
    const float* Wlin = (const float*)d_in[7];
    const float* blin = (const float*)d_in[8];
    float* out = (float*)d_out;

    const int* src = ei;
    const int* dst = ei + NE;

    // workspace bump allocator (256B aligned)
    char* ws = (char*)d_ws;
    size_t off = 0;
    auto alloc = [&](size_t bytes) {
        char* p = ws + off;
        off += (bytes + 255) & ~(size_t)255;
        return p;
    };
    int*   cnt_i = (int*)  alloc(NN * sizeof(int));
    float* dinv  = (float*)alloc(NN * sizeof(float));
    float* A     = (float*)alloc((size_t)NN * HD * sizeof(float)); // xw
    float* B     = (float*)alloc((size_t)NN * HD * sizeof(float)); // agg
    float* C     = (float*)alloc((size_t)NN * HD * sizeof(float)); // h
    float* pool  = (float*)alloc((size_t)NG * HD * sizeof(float));
    float* pcnt  = (float*)alloc((size_t)NG * sizeof(float));
    (void)ws_size; (void)n_in; (void)in_sizes; (void)out_size;

    const int BLK = 256;
    const long long NH = (long long)NN * HD;        // 6.4M
    const long long EH = (long long)NE * HD;        // 204.8M
    const int gNH = (int)((NH + BLK - 1) / BLK);
    const int gEH = (int)((EH + BLK - 1) / BLK);

    // degrees (shared by both layers)
    hipMemsetAsync(cnt_i, 0, NN * sizeof(int), stream);
    deg_count_k<<<(NE + BLK - 1) / BLK, BLK, 0, stream>>>(dst, cnt_i, NE);
    dinv_k<<<(NN + BLK - 1) / BLK, BLK, 0, stream>>>(cnt_i, dinv, NN);

    // ---- layer 1 ----
    xw1_k<<<gNH, BLK, 0, stream>>>(x, W1, A, NN);
    hipMemsetAsync(B, 0, (size_t)NN * HD * sizeof(float), stream);
    scatter_k<<<gEH, BLK, 0, stream>>>(A, src, dst, dinv, B);
    combine_k<<<gNH, BLK, 0, stream>>>(B, A, dinv, b1, C, NN);

    // ---- layer 2 ----
    xw2_k<<<gNH, BLK, 0, stream>>>(C, W2, A, NN);
    hipMemsetAsync(B, 0, (size_t)NN * HD * sizeof(float), stream);
    scatter_k<<<gEH, BLK, 0, stream>>>(A, src, dst, dinv, B);
    combine_k<<<gNH, BLK, 0, stream>>>(B, A, dinv, b2, C, NN);

    // ---- pool + linear ----
    hipMemsetAsync(pool, 0, (size_t)NG * HD * sizeof(float), stream);
    hipMemsetAsync(pcnt, 0, (size_t)NG * sizeof(float), stream);
    pool_k<<<gNH, BLK, 0, stream>>>(C, bat, pool, NN);
    cnt_k<<<(NN + BLK - 1) / BLK, BLK, 0, stream>>>(bat, pcnt, NN);
    final_k<<<NG, 64, 0, stream>>>(pool, pcnt, Wlin, blin, out);
}

// Round 2
// 776.076 us; speedup vs baseline: 2.2007x; 2.2007x over previous
//
#include <hip/hip_runtime.h>

#define NN 100000
#define NE 3200000
#define NG 2048
#define FIN 4
#define HD 64
#define SBLK 256

// ---------------- degree / norm ----------------

__global__ void deg_count_k(const int* __restrict__ dst, int* __restrict__ cnt, int e) {
    int t = blockIdx.x * blockDim.x + threadIdx.x;
    if (t < e) atomicAdd(&cnt[dst[t]], 1);
}

__global__ void dinv_k(const int* __restrict__ cnt, float* __restrict__ dinv, int n) {
    int t = blockIdx.x * blockDim.x + threadIdx.x;
    if (t < n) dinv[t] = rsqrtf((float)cnt[t] + 1.0f);
}

// ---------------- CSR build: 3-kernel scan + fill ----------------

__global__ void scan1_k(const int* __restrict__ cnt, int* __restrict__ bsum, int n) {
    __shared__ int s[SBLK];
    int i = blockIdx.x * SBLK + threadIdx.x;
    s[threadIdx.x] = (i < n) ? cnt[i] : 0;
    __syncthreads();
    for (int o = SBLK / 2; o > 0; o >>= 1) {
        if (threadIdx.x < o) s[threadIdx.x] += s[threadIdx.x + o];
        __syncthreads();
    }
    if (threadIdx.x == 0) bsum[blockIdx.x] = s[0];
}

// single block: exclusive scan of nb (<=1024) block sums
__global__ void scan2_k(int* __restrict__ bsum, int nb) {
    __shared__ int s[1024];
    int t = threadIdx.x;
    int v = (t < nb) ? bsum[t] : 0;
    s[t] = v;
    __syncthreads();
    for (int o = 1; o < 1024; o <<= 1) {
        int u = (t >= o) ? s[t - o] : 0;
        __syncthreads();
        if (t >= o) s[t] += u;
        __syncthreads();
    }
    if (t < nb) bsum[t] = s[t] - v;   // exclusive
}

__global__ void scan3_k(const int* __restrict__ cnt, const int* __restrict__ bpre,
                        int* __restrict__ row_ptr, int* __restrict__ wcur, int n) {
    __shared__ int s[SBLK];
    int i = blockIdx.x * SBLK + threadIdx.x;
    int v = (i < n) ? cnt[i] : 0;
    s[threadIdx.x] = v;
    __syncthreads();
    for (int o = 1; o < SBLK; o <<= 1) {
        int u = (threadIdx.x >= o) ? s[threadIdx.x - o] : 0;
        __syncthreads();
        if (threadIdx.x >= o) s[threadIdx.x] += u;
        __syncthreads();
    }
    int excl = s[threadIdx.x] - v + bpre[blockIdx.x];
    if (i < n) { row_ptr[i] = excl; wcur[i] = excl; }
    if (i == n - 1) row_ptr[n] = excl + v;
}

__global__ void fill_k(const int* __restrict__ src, const int* __restrict__ dst,
                       int* __restrict__ wcur, int* __restrict__ csr_src, int e) {
    int t = blockIdx.x * blockDim.x + threadIdx.x;
    if (t < e) {
        int pos = atomicAdd(&wcur[dst[t]], 1);
        csr_src[pos] = src[t];
    }
}

// ---------------- dense xW (pre-scaled by dinv) ----------------

// xws = dinv[node] * (x @ W1), x [n,FIN], W1 [FIN,HD]
__global__ void xw1_k(const float* __restrict__ x, const float* __restrict__ W,
                      const float* __restrict__ dinv, float* __restrict__ out, int n) {
    int t = blockIdx.x * blockDim.x + threadIdx.x;
    if (t >= n * HD) return;
    int node = t >> 6, h = t & 63;
    const float* xp = x + node * FIN;
    float s = 0.f;
#pragma unroll
    for (int k = 0; k < FIN; ++k) s = fmaf(xp[k], W[k * HD + h], s);
    out[t] = s * dinv[node];
}

// xws = dinv[node] * (hin @ W2), hin [n,HD], W2 [HD,HD] in LDS
__global__ void xw2_k(const float* __restrict__ hin, const float* __restrict__ W,
                      const float* __restrict__ dinv, float* __restrict__ out, int n) {
    __shared__ float w[HD * HD];
    for (int i = threadIdx.x; i < HD * HD; i += blockDim.x) w[i] = W[i];
    __syncthreads();
    int t = blockIdx.x * blockDim.x + threadIdx.x;
    if (t >= n * HD) return;
    int node = t >> 6, h = t & 63;
    const float* hp = hin + node * HD;
    float s = 0.f;
#pragma unroll
    for (int k = 0; k < HD; ++k) s = fmaf(hp[k], w[k * HD + h], s);
    out[t] = s * dinv[node];
}

// ---------------- gather layers ----------------
// one wave per dst node, lane = feature h
// out_node = relu( dinv[d] * (sum_{s in N(d)} xws[s] + xws[d]) + bias )

__global__ void gather1_k(const float* __restrict__ xws, const int* __restrict__ csr_src,
                          const int* __restrict__ row_ptr, const float* __restrict__ dinv,
                          const float* __restrict__ bias, float* __restrict__ out) {
    int wid = (blockIdx.x * blockDim.x + threadIdx.x) >> 6;
    int lane = threadIdx.x & 63;
    if (wid >= NN) return;
    int beg = row_ptr[wid], end = row_ptr[wid + 1];
    float acc = xws[(size_t)wid * HD + lane];   // self term
    int e = beg;
    for (; e + 4 <= end; e += 4) {
        int s0 = csr_src[e], s1 = csr_src[e + 1], s2 = csr_src[e + 2], s3 = csr_src[e + 3];
        float a0 = xws[(size_t)s0 * HD + lane];
        float a1 = xws[(size_t)s1 * HD + lane];
        float a2 = xws[(size_t)s2 * HD + lane];
        float a3 = xws[(size_t)s3 * HD + lane];
        acc += a0 + a1 + a2 + a3;
    }
    for (; e < end; ++e) acc += xws[(size_t)csr_src[e] * HD + lane];
    float v = fmaxf(fmaf(dinv[wid], acc, bias[lane]), 0.f);
    out[(size_t)wid * HD + lane] = v;
}

// layer-2 gather fused with mean-pool accumulation (no h2 materialization)
__global__ void gather2_pool_k(const float* __restrict__ xws, const int* __restrict__ csr_src,
                               const int* __restrict__ row_ptr, const float* __restrict__ dinv,
                               const float* __restrict__ bias, const int* __restrict__ batch,
                               float* __restrict__ pool) {
    int wid = (blockIdx.x * blockDim.x + threadIdx.x) >> 6;
    int lane = threadIdx.x & 63;
    if (wid >= NN) return;
    int beg = row_ptr[wid], end = row_ptr[wid + 1];
    float acc = xws[(size_t)wid * HD + lane];
    int e = beg;
    for (; e + 4 <= end; e += 4) {
        int s0 = csr_src[e], s1 = csr_src[e + 1], s2 = csr_src[e + 2], s3 = csr_src[e + 3];
        float a0 = xws[(size_t)s0 * HD + lane];
        float a1 = xws[(size_t)s1 * HD + lane];
        float a2 = xws[(size_t)s2 * HD + lane];
        float a3 = xws[(size_t)s3 * HD + lane];
        acc += a0 + a1 + a2 + a3;
    }
    for (; e < end; ++e) acc += xws[(size_t)csr_src[e] * HD + lane];
    float v = fmaxf(fmaf(dinv[wid], acc, bias[lane]), 0.f);
    atomicAdd(&pool[(size_t)batch[wid] * HD + lane], v);
}

__global__ void cnt_k(const int* __restrict__ batch, float* __restrict__ pcnt, int n) {
    int t = blockIdx.x * blockDim.x + threadIdx.x;
    if (t < n) atomicAdd(&pcnt[batch[t]], 1.0f);
}

// one wave per graph: out[g] = dot(pool[g]/cnt[g], Wlin) + blin
__global__ void final_k(const float* __restrict__ pool, const float* __restrict__ pcnt,
                        const float* __restrict__ Wlin, const float* __restrict__ blin,
                        float* __restrict__ out) {
    int g = blockIdx.x;
    int lane = threadIdx.x;
    float v = pool[g * HD + lane] * Wlin[lane];
#pragma unroll
    for (int off = 32; off > 0; off >>= 1) v += __shfl_down(v, off);
    if (lane == 0) out[g] = v / fmaxf(pcnt[g], 1.0f) + blin[0];
}

// ---------------- launch ----------------

extern "C" void kernel_launch(void* const* d_in, const int* in_sizes, int n_in,
                              void* d_out, int out_size, void* d_ws, size_t ws_size,
                              hipStream_t stream) {
    const float* x    = (const float*)d_in[0];
    const int*   ei   = (const int*)d_in[1];
    const int*   bat  = (const int*)d_in[2];
    const float* W1   = (const float*)d_in[3];
    const float* b1   = (const float*)d_in[4];
    const float* W2   = (const float*)d_in[5];
    const float* b2   = (const float*)d_in[6];
    const float* Wlin = (const float*)d_in[7];
    const float* blin = (const float*)d_in[8];
    float* out = (float*)d_out;

    const int* src = ei;
    const int* dst = ei + NE;

    char* ws = (char*)d_ws;
    size_t off = 0;
    auto alloc = [&](size_t bytes) {
        char* p = ws + off;
        off += (bytes + 255) & ~(size_t)255;
        return p;
    };
    int*   cnt_i   = (int*)  alloc(NN * sizeof(int));
    float* dinv    = (float*)alloc(NN * sizeof(float));
    int*   bsum    = (int*)  alloc(1024 * sizeof(int));
    int*   row_ptr = (int*)  alloc((NN + 1) * sizeof(int));
    int*   wcur    = (int*)  alloc(NN * sizeof(int));
    int*   csr_src = (int*)  alloc((size_t)NE * sizeof(int));
    float* A       = (float*)alloc((size_t)NN * HD * sizeof(float)); // xws
    float* C       = (float*)alloc((size_t)NN * HD * sizeof(float)); // h1
    float* pool    = (float*)alloc((size_t)NG * HD * sizeof(float));
    float* pcnt    = (float*)alloc((size_t)NG * sizeof(float));
    (void)ws_size; (void)n_in; (void)in_sizes; (void)out_size;

    const int BLK = 256;
    const int nScanBlocks = (NN + SBLK - 1) / SBLK;           // 391
    const int gE  = (NE + BLK - 1) / BLK;
    const int gN  = (NN + BLK - 1) / BLK;
    const int gNH = (int)(((long long)NN * HD + BLK - 1) / BLK);
    const int gW  = (NN * 64 + BLK - 1) / BLK;                // one wave per node

    // degrees + norm
    hipMemsetAsync(cnt_i, 0, NN * sizeof(int), stream);
    deg_count_k<<<gE, BLK, 0, stream>>>(dst, cnt_i, NE);
    dinv_k<<<gN, BLK, 0, stream>>>(cnt_i, dinv, NN);

    // CSR by dst
    scan1_k<<<nScanBlocks, SBLK, 0, stream>>>(cnt_i, bsum, NN);
    scan2_k<<<1, 1024, 0, stream>>>(bsum, nScanBlocks);
    scan3_k<<<nScanBlocks, SBLK, 0, stream>>>(cnt_i, bsum, row_ptr, wcur, NN);
    fill_k<<<gE, BLK, 0, stream>>>(src, dst, wcur, csr_src, NE);

    // layer 1
    xw1_k<<<gNH, BLK, 0, stream>>>(x, W1, dinv, A, NN);
    gather1_k<<<gW, BLK, 0, stream>>>(A, csr_src, row_ptr, dinv, b1, C);

    // layer 2 (+ fused pool)
    xw2_k<<<gNH, BLK, 0, stream>>>(C, W2, dinv, A, NN);
    hipMemsetAsync(pool, 0, (size_t)NG * HD * sizeof(float), stream);
    hipMemsetAsync(pcnt, 0, (size_t)NG * sizeof(float), stream);
    gather2_pool_k<<<gW, BLK, 0, stream>>>(A, csr_src, row_ptr, dinv, b2, bat, pool);

    // readout
    cnt_k<<<gN, BLK, 0, stream>>>(bat, pcnt, NN);
    final_k<<<NG, 64, 0, stream>>>(pool, pcnt, Wlin, blin, out);
}

// Round 3
// 441.429 us; speedup vs baseline: 3.8690x; 1.7581x over previous
//
#include <hip/hip_runtime.h>

#define NN 100000
#define NE 3200000
#define NG 2048
#define FIN 4
#define HD 64
#define NBUK 196          // ceil(100000 / 512) buckets of 512 node ids
#define NB 1024           // histogram blocks
#define CHUNK 3125        // NE / NB exactly
#define SBLK 256

// ---------------- pass 1: per-block bucket histogram ----------------

__global__ void hist_k(const int* __restrict__ dst, int* __restrict__ counts) {
    __shared__ int h[NBUK];
    for (int i = threadIdx.x; i < NBUK; i += blockDim.x) h[i] = 0;
    __syncthreads();
    int base = blockIdx.x * CHUNK;
    for (int i = threadIdx.x; i < CHUNK; i += blockDim.x)
        atomicAdd(&h[dst[base + i] >> 9], 1);
    __syncthreads();
    // counts laid out [bucket][block] for bucket-major contiguity after scan
    for (int k = threadIdx.x; k < NBUK; k += blockDim.x)
        counts[k * NB + blockIdx.x] = h[k];
}

// ---------------- flat exclusive scan of counts (n = NBUK*NB) ----------------

__global__ void scan1_k(const int* __restrict__ in, int* __restrict__ bsum, int n) {
    __shared__ int s[SBLK];
    int i = blockIdx.x * SBLK + threadIdx.x;
    s[threadIdx.x] = (i < n) ? in[i] : 0;
    __syncthreads();
    for (int o = SBLK / 2; o > 0; o >>= 1) {
        if (threadIdx.x < o) s[threadIdx.x] += s[threadIdx.x + o];
        __syncthreads();
    }
    if (threadIdx.x == 0) bsum[blockIdx.x] = s[0];
}

__global__ void scan2_k(int* __restrict__ bsum, int nb) {
    __shared__ int s[1024];
    int t = threadIdx.x;
    int v = (t < nb) ? bsum[t] : 0;
    s[t] = v;
    __syncthreads();
    for (int o = 1; o < 1024; o <<= 1) {
        int u = (t >= o) ? s[t - o] : 0;
        __syncthreads();
        if (t >= o) s[t] += u;
        __syncthreads();
    }
    if (t < nb) bsum[t] = s[t] - v;   // exclusive block prefix
}

__global__ void scan3_k(const int* __restrict__ in, const int* __restrict__ bpre,
                        int* __restrict__ out, int n) {
    __shared__ int s[SBLK];
    int i = blockIdx.x * SBLK + threadIdx.x;
    int v = (i < n) ? in[i] : 0;
    s[threadIdx.x] = v;
    __syncthreads();
    for (int o = 1; o < SBLK; o <<= 1) {
        int u = (threadIdx.x >= o) ? s[threadIdx.x - o] : 0;
        __syncthreads();
        if (threadIdx.x >= o) s[threadIdx.x] += u;
        __syncthreads();
    }
    if (i < n) out[i] = s[threadIdx.x] - v + bpre[blockIdx.x];
}

// ---------------- pass 2: scatter into block-exclusive staging ranges ----------------
// staged value packs (dst & 511) << 17 | src   (src < 2^17)

__global__ void stage_k(const int* __restrict__ src, const int* __restrict__ dst,
                        const int* __restrict__ offs, unsigned int* __restrict__ staging) {
    __shared__ int cur[NBUK];
    for (int k = threadIdx.x; k < NBUK; k += blockDim.x)
        cur[k] = offs[k * NB + blockIdx.x];
    __syncthreads();
    int base = blockIdx.x * CHUNK;
    for (int i = threadIdx.x; i < CHUNK; i += blockDim.x) {
        int d = dst[base + i];
        int s = src[base + i];
        int pos = atomicAdd(&cur[d >> 9], 1);
        staging[pos] = ((unsigned int)(d & 511) << 17) | (unsigned int)s;
    }
}

// ---------------- pass 3: per-bucket fine sort -> CSR, row_ptr, dinv ----------------

__global__ void csr_fill_bucket_k(const unsigned int* __restrict__ staging,
                                  const int* __restrict__ offs,
                                  int* __restrict__ csr_src, int* __restrict__ row_ptr,
                                  float* __restrict__ dinv) {
    __shared__ int degl[512];
    __shared__ int sc[512];
    __shared__ int cur[512];
    int k = blockIdx.x;
    int t = threadIdx.x;
    int nodeBase = k << 9;
    int s0 = offs[k * NB];
    int s1 = (k < NBUK - 1) ? offs[(k + 1) * NB] : NE;
    degl[t] = 0;
    __syncthreads();
    for (int i = s0 + t; i < s1; i += 512)
        atomicAdd(&degl[staging[i] >> 17], 1);
    __syncthreads();
    int v = degl[t];
    sc[t] = v;
    __syncthreads();
    for (int o = 1; o < 512; o <<= 1) {
        int u = (t >= o) ? sc[t - o] : 0;
        __syncthreads();
        if (t >= o) sc[t] += u;
        __syncthreads();
    }
    int excl = sc[t] - v;
    int node = nodeBase + t;
    if (node < NN) {
        row_ptr[node] = s0 + excl;
        dinv[node] = rsqrtf((float)v + 1.0f);
    }
    cur[t] = s0 + excl;
    if (k == NBUK - 1 && t == 0) row_ptr[NN] = NE;
    __syncthreads();
    for (int i = s0 + t; i < s1; i += 512) {
        unsigned int pv = staging[i];
        int pos = atomicAdd(&cur[pv >> 17], 1);
        csr_src[pos] = (int)(pv & 0x1FFFFu);
    }
}

// ---------------- dense xW (pre-scaled by dinv) ----------------

__global__ void xw1_k(const float* __restrict__ x, const float* __restrict__ W,
                      const float* __restrict__ dinv, float* __restrict__ out, int n) {
    int t = blockIdx.x * blockDim.x + threadIdx.x;
    if (t >= n * HD) return;
    int node = t >> 6, h = t & 63;
    const float* xp = x + node * FIN;
    float s = 0.f;
#pragma unroll
    for (int k = 0; k < FIN; ++k) s = fmaf(xp[k], W[k * HD + h], s);
    out[t] = s * dinv[node];
}

__global__ void xw2_k(const float* __restrict__ hin, const float* __restrict__ W,
                      const float* __restrict__ dinv, float* __restrict__ out, int n) {
    __shared__ float w[HD * HD];
    for (int i = threadIdx.x; i < HD * HD; i += blockDim.x) w[i] = W[i];
    __syncthreads();
    int t = blockIdx.x * blockDim.x + threadIdx.x;
    if (t >= n * HD) return;
    int node = t >> 6, h = t & 63;
    const float* hp = hin + node * HD;
    float s = 0.f;
#pragma unroll
    for (int k = 0; k < HD; ++k) s = fmaf(hp[k], w[k * HD + h], s);
    out[t] = s * dinv[node];
}

// ---------------- gather layers (one wave per dst node, lane = feature) ----------------

__global__ void gather1_k(const float* __restrict__ xws, const int* __restrict__ csr_src,
                          const int* __restrict__ row_ptr, const float* __restrict__ dinv,
                          const float* __restrict__ bias, float* __restrict__ out) {
    int wid = (blockIdx.x * blockDim.x + threadIdx.x) >> 6;
    int lane = threadIdx.x & 63;
    if (wid >= NN) return;
    int beg = row_ptr[wid], end = row_ptr[wid + 1];
    float acc = xws[(size_t)wid * HD + lane];
    int e = beg;
    for (; e + 4 <= end; e += 4) {
        int s0 = csr_src[e], s1 = csr_src[e + 1], s2 = csr_src[e + 2], s3 = csr_src[e + 3];
        float a0 = xws[(size_t)s0 * HD + lane];
        float a1 = xws[(size_t)s1 * HD + lane];
        float a2 = xws[(size_t)s2 * HD + lane];
        float a3 = xws[(size_t)s3 * HD + lane];
        acc += a0 + a1 + a2 + a3;
    }
    for (; e < end; ++e) acc += xws[(size_t)csr_src[e] * HD + lane];
    float v = fmaxf(fmaf(dinv[wid], acc, bias[lane]), 0.f);
    out[(size_t)wid * HD + lane] = v;
}

__global__ void gather2_pool_k(const float* __restrict__ xws, const int* __restrict__ csr_src,
                               const int* __restrict__ row_ptr, const float* __restrict__ dinv,
                               const float* __restrict__ bias, const int* __restrict__ batch,
                               float* __restrict__ pool) {
    int wid = (blockIdx.x * blockDim.x + threadIdx.x) >> 6;
    int lane = threadIdx.x & 63;
    if (wid >= NN) return;
    int beg = row_ptr[wid], end = row_ptr[wid + 1];
    float acc = xws[(size_t)wid * HD + lane];
    int e = beg;
    for (; e + 4 <= end; e += 4) {
        int s0 = csr_src[e], s1 = csr_src[e + 1], s2 = csr_src[e + 2], s3 = csr_src[e + 3];
        float a0 = xws[(size_t)s0 * HD + lane];
        float a1 = xws[(size_t)s1 * HD + lane];
        float a2 = xws[(size_t)s2 * HD + lane];
        float a3 = xws[(size_t)s3 * HD + lane];
        acc += a0 + a1 + a2 + a3;
    }
    for (; e < end; ++e) acc += xws[(size_t)csr_src[e] * HD + lane];
    float v = fmaxf(fmaf(dinv[wid], acc, bias[lane]), 0.f);
    atomicAdd(&pool[(size_t)batch[wid] * HD + lane], v);
}

__global__ void cnt_k(const int* __restrict__ batch, float* __restrict__ pcnt, int n) {
    int t = blockIdx.x * blockDim.x + threadIdx.x;
    if (t < n) atomicAdd(&pcnt[batch[t]], 1.0f);
}

__global__ void final_k(const float* __restrict__ pool, const float* __restrict__ pcnt,
                        const float* __restrict__ Wlin, const float* __restrict__ blin,
                        float* __restrict__ out) {
    int g = blockIdx.x;
    int lane = threadIdx.x;
    float v = pool[g * HD + lane] * Wlin[lane];
#pragma unroll
    for (int off = 32; off > 0; off >>= 1) v += __shfl_down(v, off);
    if (lane == 0) out[g] = v / fmaxf(pcnt[g], 1.0f) + blin[0];
}

// ---------------- launch ----------------

extern "C" void kernel_launch(void* const* d_in, const int* in_sizes, int n_in,
                              void* d_out, int out_size, void* d_ws, size_t ws_size,
                              hipStream_t stream) {
    const float* x    = (const float*)d_in[0];
    const int*   ei   = (const int*)d_in[1];
    const int*   bat  = (const int*)d_in[2];
    const float* W1   = (const float*)d_in[3];
    const float* b1   = (const float*)d_in[4];
    const float* W2   = (const float*)d_in[5];
    const float* b2   = (const float*)d_in[6];
    const float* Wlin = (const float*)d_in[7];
    const float* blin = (const float*)d_in[8];
    float* out = (float*)d_out;

    const int* src = ei;
    const int* dst = ei + NE;

    char* ws = (char*)d_ws;
    size_t off = 0;
    auto alloc = [&](size_t bytes) {
        char* p = ws + off;
        off += (bytes + 255) & ~(size_t)255;
        return p;
    };
    const int NCNT = NBUK * NB;                       // 200704
    int*   counts  = (int*)  alloc(NCNT * sizeof(int));
    int*   offs    = (int*)  alloc(NCNT * sizeof(int));
    int*   bsum    = (int*)  alloc(1024 * sizeof(int));
    int*   row_ptr = (int*)  alloc((NN + 1) * sizeof(int));
    float* dinv    = (float*)alloc(NN * sizeof(float));
    int*   csr_src = (int*)  alloc((size_t)NE * sizeof(int));
    float* A       = (float*)alloc((size_t)NN * HD * sizeof(float)); // xws
    float* C       = (float*)alloc((size_t)NN * HD * sizeof(float)); // h1
    float* pool    = (float*)alloc((size_t)NG * HD * sizeof(float));
    float* pcnt    = (float*)alloc((size_t)NG * sizeof(float));
    // staging aliases C: staging is dead before gather1 writes C
    unsigned int* staging = (unsigned int*)C;
    (void)ws_size; (void)n_in; (void)in_sizes; (void)out_size;

    const int BLK = 256;
    const int nScanBlocks = (NCNT + SBLK - 1) / SBLK;   // 784
    const int gN  = (NN + BLK - 1) / BLK;
    const int gNH = (int)(((long long)NN * HD + BLK - 1) / BLK);
    const int gW  = (NN * 64 + BLK - 1) / BLK;

    // CSR build (no global atomics, block-exclusive write regions)
    hist_k<<<NB, BLK, 0, stream>>>(dst, counts);
    scan1_k<<<nScanBlocks, SBLK, 0, stream>>>(counts, bsum, NCNT);
    scan2_k<<<1, 1024, 0, stream>>>(bsum, nScanBlocks);
    scan3_k<<<nScanBlocks, SBLK, 0, stream>>>(counts, bsum, offs, NCNT);
    stage_k<<<NB, BLK, 0, stream>>>(src, dst, offs, staging);
    csr_fill_bucket_k<<<NBUK, 512, 0, stream>>>(staging, offs, csr_src, row_ptr, dinv);

    // layer 1
    xw1_k<<<gNH, BLK, 0, stream>>>(x, W1, dinv, A, NN);
    gather1_k<<<gW, BLK, 0, stream>>>(A, csr_src, row_ptr, dinv, b1, C);

    // layer 2 (+ fused pool)
    xw2_k<<<gNH, BLK, 0, stream>>>(C, W2, dinv, A, NN);
    hipMemsetAsync(pool, 0, (size_t)NG * HD * sizeof(float), stream);
    hipMemsetAsync(pcnt, 0, (size_t)NG * sizeof(float), stream);
    gather2_pool_k<<<gW, BLK, 0, stream>>>(A, csr_src, row_ptr, dinv, b2, bat, pool);

    // readout
    cnt_k<<<gN, BLK, 0, stream>>>(bat, pcnt, NN);
    final_k<<<NG, 64, 0, stream>>>(pool, pcnt, Wlin, blin, out);
}